// Round 6
// baseline (1869.072 us; speedup 1.0000x reference)
//
#include <hip/hip_runtime.h>
#include <hip/hip_bf16.h>
#include <math.h>

using bf16 = __hip_bfloat16;

#define NB 1024   // batch
#define NT 64     // encoder length
#define ND 512    // input size D
#define NH 512    // hidden H
#define NC 96     // classes
#define NS 21     // decode steps
#define NDC 608   // D + C
#define NG 2048   // 4H

// ---- workspace layout (float offsets) ----
#define OFF_HPB   0u          /* 16,777,216 : Hp bf16 [B*T,H] */
#define OFF_BHB   16777216u   /* 16,777,216 : batch_H bf16    */
#define OFF_C     33554432u   /* 524,288    : c fp32 [B,H]    */
#define OFF_HB16  34078720u   /* 262,144    : h bf16 [B,H]    */
#define OFF_PH    34340864u   /* 262,144    : ph bf16 [B,H]   */
#define OFF_CTXB  34865152u   /* 262,144    : ctx bf16 [B,D]  */
#define OFF_WIB   35127296u   /* 131,072    : Wi bf16 [512,512] */
#define OFF_WCB   35258368u   /* 163,840    : [Wh(512);Wg(96);pad(32)] bf16 [640,512] */
#define OFF_W2    35422208u   /* 1,048,576  : W2 bf16 [2048,1024] gate-interleaved */
#define OFF_BH_   36470784u   /* 512  : bh fp32      */
#define OFF_BIHH  36471296u   /* 2048 : bih+bhh fp32 */
#define OFF_WS_   36473344u   /* 512  : Ws fp32      */
#define OFF_BG_   36473856u   /* 96 (pad 128) : bg fp32 */
#define OFF_OH    36473984u   /* 196,608 : onehotT fp32 [96][2048] */
#define WS_NEED_FLOATS 36670592u
#define WS_NEED_BYTES ((size_t)WS_NEED_FLOATS * 4u)

typedef __attribute__((ext_vector_type(8))) short bf16x8;
typedef __attribute__((ext_vector_type(4))) float f32x4;

__device__ __forceinline__ unsigned short f2bu(float f) {
    unsigned u = __float_as_uint(f);
    unsigned r = (u + 0x7fffu + ((u >> 16) & 1u)) >> 16;  // RNE
    return (unsigned short)r;
}
__device__ __forceinline__ float b2f(short s) {
    return __uint_as_float(((unsigned)(unsigned short)s) << 16);
}
__device__ __forceinline__ float fast_sigmoid(float x) {
    return 1.f / (1.f + __expf(-x));
}
__device__ __forceinline__ float fast_tanh(float x) {
    x = fminf(15.f, fmaxf(-15.f, x));
    float e = __expf(2.f * x);
    return (e - 1.f) / (e + 1.f);
}

// ---------------- merged conversion + state zeroing ----------------
#define BH_BLOCKS 32768u   /* (1024*64*512)/(256*4) */
#define W_ELEMS   2886752u
#define W_BLOCKS  11277u   /* ceil(W_ELEMS/256) */
#define Z_BLOCKS  768u     /* (524288+262144)/(256*4) */

__global__ __launch_bounds__(256) void conv_all(
    const float* __restrict__ bHsrc,
    const float* __restrict__ Wi, const float* __restrict__ Wh, const float* __restrict__ bh,
    const float* __restrict__ Ws, const float* __restrict__ Wih, const float* __restrict__ Whh,
    const float* __restrict__ bih, const float* __restrict__ bhh, const float* __restrict__ Wg,
    const float* __restrict__ bg, float* __restrict__ ws) {
    if (blockIdx.x < BH_BLOCKS) {
        unsigned short* dst = (unsigned short*)(ws + OFF_BHB);
        size_t i = ((size_t)blockIdx.x * 256 + threadIdx.x) * 4;
        float4 v = *(const float4*)(bHsrc + i);
        uint2 pk;
        pk.x = (unsigned)f2bu(v.x) | ((unsigned)f2bu(v.y) << 16);
        pk.y = (unsigned)f2bu(v.z) | ((unsigned)f2bu(v.w) << 16);
        *(uint2*)&dst[i] = pk;
        return;
    }
    if (blockIdx.x >= BH_BLOCKS + W_BLOCKS) {
        // zero c (fp32) + h (bf16): contiguous 786,432 floats at OFF_C
        unsigned iz = blockIdx.x - (BH_BLOCKS + W_BLOCKS);
        size_t o = OFF_C + ((size_t)iz * 256 + threadIdx.x) * 4;
        *(float4*)(ws + o) = (float4){0.f, 0.f, 0.f, 0.f};
        return;
    }
    unsigned i = (blockIdx.x - BH_BLOCKS) * 256u + threadIdx.x;
    if (i >= W_ELEMS) return;
    unsigned short* WiB = (unsigned short*)(ws + OFF_WIB);
    unsigned short* WcB = (unsigned short*)(ws + OFF_WCB);
    unsigned short* W2B = (unsigned short*)(ws + OFF_W2);
    if (i < 262144u) {
        WiB[i] = f2bu(Wi[i]);
    } else if (i < 524288u) {
        unsigned j = i - 262144u;             // Wh -> WcB rows 0..511
        WcB[j] = f2bu(Wh[j]);
    } else if (i < 573440u) {
        unsigned j = i - 524288u;             // Wg -> WcB rows 512..607
        WcB[262144u + j] = f2bu(Wg[j]);
    } else if (i < 589824u) {
        unsigned j = i - 573440u;             // pad rows 608..639
        WcB[311296u + j] = 0;
    } else if (i < 2686976u) {
        unsigned j = i - 589824u;             // W2 [2048,1024] gate-interleaved
        unsigned r = j >> 10, k = j & 1023u;
        unsigned K = r >> 8, rem = r & 255u;
        unsigned g = rem >> 6, jj = rem & 63u;
        unsigned srow = g * 512u + K * 64u + jj;
        float v = (k < 512u) ? Whh[(size_t)srow * 512u + k]
                             : Wih[(size_t)srow * NDC + (k - 512u)];
        W2B[j] = f2bu(v);
    } else if (i < 2687488u) {
        unsigned j = i - 2686976u;
        ws[OFF_BH_ + j] = bh[j];
    } else if (i < 2689536u) {
        unsigned j = i - 2687488u;
        ws[OFF_BIHH + j] = bih[j] + bhh[j];
    } else if (i < 2690048u) {
        unsigned j = i - 2689536u;
        ws[OFF_WS_ + j] = Ws[j];
    } else if (i < 2690144u) {
        unsigned j = i - 2690048u;
        ws[OFF_BG_ + j] = bg[j];
    } else {
        unsigned j = i - 2690144u;            // onehotT[c][n] = Wih[n*608 + 512 + c]
        unsigned c = j >> 11, n = j & 2047u;
        ws[OFF_OH + j] = Wih[(size_t)n * NDC + ND + c];
    }
}

// ---------------- Hp GEMM (bf16 MFMA, 128x128 tile) ----------------
__global__ __launch_bounds__(256) void hp_gemm(const bf16* __restrict__ A,
                                               const bf16* __restrict__ B,
                                               bf16* __restrict__ outB) {
    __shared__ short As[128 * 40];
    __shared__ short Bs[128 * 40];
    const int tid = threadIdx.x;
    const int wave = tid >> 6, lane = tid & 63;
    const int wrow = wave >> 1, wcol = wave & 1;
    const int quad = lane >> 4, l16 = lane & 15;
    const int m0 = blockIdx.x * 128, n0 = blockIdx.y * 128;
    f32x4 acc[4][4];
    #pragma unroll
    for (int mi = 0; mi < 4; ++mi)
        #pragma unroll
        for (int ni = 0; ni < 4; ++ni) acc[mi][ni] = (f32x4){0.f, 0.f, 0.f, 0.f};
    for (int k0 = 0; k0 < 512; k0 += 32) {
        #pragma unroll
        for (int l = 0; l < 2; ++l) {
            int c = tid + l * 256;
            int row = c >> 2, c8 = c & 3;
            *(uint4*)&As[row * 40 + c8 * 8] =
                *(const uint4*)&A[(size_t)(m0 + row) * 512 + k0 + c8 * 8];
            *(uint4*)&Bs[row * 40 + c8 * 8] =
                *(const uint4*)&B[(size_t)(n0 + row) * 512 + k0 + c8 * 8];
        }
        __syncthreads();
        bf16x8 af[4], bfr[4];
        #pragma unroll
        for (int mi = 0; mi < 4; ++mi)
            af[mi] = *(const bf16x8*)&As[(wrow * 64 + mi * 16 + l16) * 40 + quad * 8];
        #pragma unroll
        for (int ni = 0; ni < 4; ++ni)
            bfr[ni] = *(const bf16x8*)&Bs[(wcol * 64 + ni * 16 + l16) * 40 + quad * 8];
        #pragma unroll
        for (int mi = 0; mi < 4; ++mi)
            #pragma unroll
            for (int ni = 0; ni < 4; ++ni)
                acc[mi][ni] = __builtin_amdgcn_mfma_f32_16x16x32_bf16(af[mi], bfr[ni],
                                                                      acc[mi][ni], 0, 0, 0);
        __syncthreads();
    }
    #pragma unroll
    for (int mi = 0; mi < 4; ++mi)
        #pragma unroll
        for (int ni = 0; ni < 4; ++ni)
            #pragma unroll
            for (int r = 0; r < 4; ++r) {
                int m = m0 + wrow * 64 + mi * 16 + quad * 4 + r;
                int n = n0 + wcol * 64 + ni * 16 + l16;
                outB[(size_t)m * 512 + n] = __float2bfloat16(acc[mi][ni][r]);
            }
}

// ---------------- ph+probs GEMM: [ph(bf16) | probs(s-1)] = h @ [Wh;Wg]^T ----------------
// M=1024, N=640 (512 ph + 96 probs + 32 pad), K=512. BM=128, BN=64.
__global__ __launch_bounds__(256) void ph_gemm(const bf16* __restrict__ A,
                                               const bf16* __restrict__ B,
                                               const float* __restrict__ bh,
                                               const float* __restrict__ bg,
                                               unsigned short* __restrict__ phB,
                                               float* __restrict__ out, int s) {
    __shared__ short As[128 * 40];
    __shared__ short Bs[64 * 40];
    const int tid = threadIdx.x;
    const int wave = tid >> 6, lane = tid & 63;
    const int wrow = wave >> 1, wcol = wave & 1;
    const int quad = lane >> 4, l16 = lane & 15;
    const int m0 = blockIdx.x * 128, n0 = blockIdx.y * 64;
    f32x4 acc[4][2];
    #pragma unroll
    for (int mi = 0; mi < 4; ++mi)
        #pragma unroll
        for (int ni = 0; ni < 2; ++ni) acc[mi][ni] = (f32x4){0.f, 0.f, 0.f, 0.f};
    for (int k0 = 0; k0 < 512; k0 += 32) {
        #pragma unroll
        for (int l = 0; l < 2; ++l) {
            int c = tid + l * 256;
            int row = c >> 2, c8 = c & 3;
            *(uint4*)&As[row * 40 + c8 * 8] =
                *(const uint4*)&A[(size_t)(m0 + row) * 512 + k0 + c8 * 8];
        }
        {
            int row = tid >> 2, c8 = tid & 3;
            *(uint4*)&Bs[row * 40 + c8 * 8] =
                *(const uint4*)&B[(size_t)(n0 + row) * 512 + k0 + c8 * 8];
        }
        __syncthreads();
        bf16x8 af[4], bfr[2];
        #pragma unroll
        for (int mi = 0; mi < 4; ++mi)
            af[mi] = *(const bf16x8*)&As[(wrow * 64 + mi * 16 + l16) * 40 + quad * 8];
        #pragma unroll
        for (int ni = 0; ni < 2; ++ni)
            bfr[ni] = *(const bf16x8*)&Bs[(wcol * 32 + ni * 16 + l16) * 40 + quad * 8];
        #pragma unroll
        for (int mi = 0; mi < 4; ++mi)
            #pragma unroll
            for (int ni = 0; ni < 2; ++ni)
                acc[mi][ni] = __builtin_amdgcn_mfma_f32_16x16x32_bf16(af[mi], bfr[ni],
                                                                      acc[mi][ni], 0, 0, 0);
        __syncthreads();
    }
    #pragma unroll
    for (int mi = 0; mi < 4; ++mi) {
        #pragma unroll
        for (int ni = 0; ni < 2; ++ni) {
            #pragma unroll
            for (int r = 0; r < 4; ++r) {
                int m = m0 + wrow * 64 + mi * 16 + quad * 4 + r;
                int n = n0 + wcol * 32 + ni * 16 + l16;
                float v = acc[mi][ni][r];
                if (n < NH) {
                    phB[(size_t)m * NH + n] = f2bu(v + bh[n]);
                } else if (n < NH + NC) {
                    if (s > 0)
                        out[(size_t)m * (NS * NC) + (s - 1) * NC + (n - NH)] =
                            v + bg[n - NH];
                }
            }
        }
    }
}

// ---------------- fused attention: score + softmax + context (bf16 out) ----------------
__global__ __launch_bounds__(256, 4) void attn_fused(const bf16* __restrict__ Hp,
                                                     const bf16* __restrict__ phB,
                                                     const float* __restrict__ Wsv,
                                                     const bf16* __restrict__ bH,
                                                     unsigned short* __restrict__ ctxB) {
    const int b = blockIdx.x;
    const int tid = threadIdx.x;
    const int wave = tid >> 6, lane = tid & 63;
    __shared__ float tr[64 * 65];
    __shared__ float salpha[NT];
    __shared__ float red[4][520];
    bf16x8 phv = *(const bf16x8*)(phB + (size_t)b * NH + lane * 8);
    float4 wsa = *(const float4*)(Wsv + lane * 8);
    float4 wsb = *(const float4*)(Wsv + lane * 8 + 4);
    float ph8[8], ws8[8];
    #pragma unroll
    for (int j = 0; j < 8; ++j) ph8[j] = b2f(phv[j]);
    ws8[0] = wsa.x; ws8[1] = wsa.y; ws8[2] = wsa.z; ws8[3] = wsa.w;
    ws8[4] = wsb.x; ws8[5] = wsb.y; ws8[6] = wsb.z; ws8[7] = wsb.w;
    const bf16* hpb = Hp + ((size_t)b * NT + wave * 16) * NH + lane * 8;
    float acc[16];
    #pragma unroll
    for (int i = 0; i < 16; ++i) {
        bf16x8 hv = *(const bf16x8*)(hpb + (size_t)i * NH);
        float s = 0.f;
        #pragma unroll
        for (int j = 0; j < 8; ++j) s += fast_tanh(b2f(hv[j]) + ph8[j]) * ws8[j];
        acc[i] = s;
    }
    #pragma unroll
    for (int i = 0; i < 16; ++i) tr[(wave * 16 + i) * 65 + lane] = acc[i];
    __syncthreads();
    if (tid < NT) {
        const float* row = &tr[tid * 65];
        float e = 0.f;
        #pragma unroll
        for (int j = 0; j < 64; ++j) e += row[j];
        float m = e;
        #pragma unroll
        for (int off = 32; off > 0; off >>= 1) m = fmaxf(m, __shfl_xor(m, off, 64));
        float ex = __expf(e - m);
        float ssum = ex;
        #pragma unroll
        for (int off = 32; off > 0; off >>= 1) ssum += __shfl_xor(ssum, off, 64);
        salpha[tid] = ex / ssum;
    }
    __syncthreads();
    {
        const bf16* bh = bH + ((size_t)b * NT + wave * 16) * ND + lane * 8;
        float a8[8];
        #pragma unroll
        for (int u = 0; u < 8; ++u) a8[u] = 0.f;
        #pragma unroll
        for (int i = 0; i < 16; ++i) {
            float al = salpha[wave * 16 + i];
            bf16x8 v = *(const bf16x8*)(bh + (size_t)i * ND);
            #pragma unroll
            for (int u = 0; u < 8; ++u) a8[u] = fmaf(al, b2f(v[u]), a8[u]);
        }
        #pragma unroll
        for (int u = 0; u < 8; ++u) red[wave][lane * 8 + u] = a8[u];
    }
    __syncthreads();
    for (int d = tid; d < ND; d += 256) {
        float sum = red[0][d] + red[1][d] + red[2][d] + red[3][d];
        ctxB[(size_t)b * ND + d] = f2bu(sum);
    }
}

// ---------------- gates GEMM (K=1024, [h|ctx] @ W2^T) + LSTM pointwise ----------------
// Grid (m=32, kp=8). Block: m-tile 32, kp-window 64; wave g owns gate g.
// W2 rows for block kp-window K: [K*256 + g*64 + j] = gate g, col K*64+j; cols [Whh|Wih].
__global__ __launch_bounds__(256) void gates_lstm(const bf16* __restrict__ hB,
                                                  const bf16* __restrict__ ctxB,
                                                  const bf16* __restrict__ W2B,
                                                  const float* __restrict__ bihh,
                                                  const float* __restrict__ onehotT,
                                                  const int* __restrict__ text, int s,
                                                  float* __restrict__ c,
                                                  unsigned short* __restrict__ hOut) {
    __shared__ float smem[4 * 32 * 65];       // 33,280 B; unioned with staging
    short* As = (short*)smem;                 // 32 rows * 40
    short* Bs = As + 32 * 40;                 // 256 rows * 40
    float* ex = smem;                         // [4][32][65] after the k-loop
    const int tid = threadIdx.x;
    const int g = tid >> 6, lane = tid & 63;
    const int quad = lane >> 4, l16 = lane & 15;
    const int m0 = blockIdx.x * 32, KB = blockIdx.y, kp0 = KB * 64;
    f32x4 acc[2][4];
    #pragma unroll
    for (int mi = 0; mi < 2; ++mi)
        #pragma unroll
        for (int ni = 0; ni < 4; ++ni) acc[mi][ni] = (f32x4){0.f, 0.f, 0.f, 0.f};
    for (int k0 = 0; k0 < 1024; k0 += 32) {
        if (tid < 128) {
            int row = tid >> 2, c8 = tid & 3;
            const bf16* asrc = (k0 < 512)
                ? hB   + (size_t)(m0 + row) * 512 + k0 + c8 * 8
                : ctxB + (size_t)(m0 + row) * 512 + (k0 - 512) + c8 * 8;
            *(uint4*)&As[row * 40 + c8 * 8] = *(const uint4*)asrc;
        }
        #pragma unroll
        for (int l = 0; l < 4; ++l) {
            int j = tid + l * 256;
            int row = j >> 2, c8 = j & 3;
            *(uint4*)&Bs[row * 40 + c8 * 8] =
                *(const uint4*)&W2B[(size_t)(KB * 256 + row) * 1024 + k0 + c8 * 8];
        }
        __syncthreads();
        bf16x8 af[2], bfr[4];
        #pragma unroll
        for (int mi = 0; mi < 2; ++mi)
            af[mi] = *(const bf16x8*)&As[(mi * 16 + l16) * 40 + quad * 8];
        #pragma unroll
        for (int ni = 0; ni < 4; ++ni)
            bfr[ni] = *(const bf16x8*)&Bs[(g * 64 + ni * 16 + l16) * 40 + quad * 8];
        #pragma unroll
        for (int mi = 0; mi < 2; ++mi)
            #pragma unroll
            for (int ni = 0; ni < 4; ++ni)
                acc[mi][ni] = __builtin_amdgcn_mfma_f32_16x16x32_bf16(af[mi], bfr[ni],
                                                                      acc[mi][ni], 0, 0, 0);
        __syncthreads();
    }
    #pragma unroll
    for (int mi = 0; mi < 2; ++mi)
        #pragma unroll
        for (int ni = 0; ni < 4; ++ni)
            #pragma unroll
            for (int r = 0; r < 4; ++r) {
                int ml = mi * 16 + quad * 4 + r;
                int nl = ni * 16 + l16;
                ex[g * 2080 + ml * 65 + nl] = acc[mi][ni][r];
            }
    __syncthreads();
    #pragma unroll 1
    for (int t = 0; t < 8; ++t) {
        int idx = tid + t * 256;
        int ml = idx >> 6, kl = idx & 63;
        int m = m0 + ml, kp = kp0 + kl;
        int tb = text[m * NS + s];
        const float* oh = onehotT + (size_t)tb * NG;
        float ig = fast_sigmoid(ex[0 * 2080 + ml * 65 + kl] + bihh[kp] + oh[kp]);
        float fg = fast_sigmoid(ex[1 * 2080 + ml * 65 + kl] + bihh[NH + kp] + oh[NH + kp]);
        float gg = fast_tanh(ex[2 * 2080 + ml * 65 + kl] + bihh[2 * NH + kp] + oh[2 * NH + kp]);
        float og = fast_sigmoid(ex[3 * 2080 + ml * 65 + kl] + bihh[3 * NH + kp] + oh[3 * NH + kp]);
        float cn = fg * c[(size_t)m * NH + kp] + ig * gg;
        float hn = og * fast_tanh(cn);
        c[(size_t)m * NH + kp] = cn;
        hOut[(size_t)m * NH + kp] = f2bu(hn);
    }
}

// ---------------- final generator: probs row 20 = h @ Wg^T + bg ----------------
__global__ __launch_bounds__(256) void final_gen(const bf16* __restrict__ hB,
                                                 const bf16* __restrict__ WgB,
                                                 const float* __restrict__ bg,
                                                 float* __restrict__ out) {
    const int b = blockIdx.x;
    const int tid = threadIdx.x;
    __shared__ float hsm[NH];
    for (int k = tid; k < NH; k += 256) hsm[k] = b2f(*(const short*)&hB[(size_t)b * NH + k]);
    __syncthreads();
    if (tid < 2 * NC) {
        int oc = tid >> 1, half = tid & 1;
        const bf16* w = WgB + (size_t)oc * NH + half * 256;
        float a = 0.f;
        #pragma unroll 4
        for (int j = 0; j < 32; ++j) {
            bf16x8 w8 = *(const bf16x8*)(w + j * 8);
            #pragma unroll
            for (int u = 0; u < 8; ++u)
                a = fmaf(b2f(w8[u]), hsm[half * 256 + j * 8 + u], a);
        }
        a += __shfl_xor(a, 1, 64);
        if (half == 0)
            out[(size_t)b * (NS * NC) + 20 * NC + oc] = a + bg[oc];
    }
}

extern "C" void kernel_launch(void* const* d_in, const int* in_sizes, int n_in,
                              void* d_out, int out_size, void* d_ws, size_t ws_size,
                              hipStream_t stream) {
    if (ws_size < WS_NEED_BYTES) {
        hipMemsetAsync(d_out, 0x7F, (size_t)out_size * 4, stream);
        return;
    }
    float* ws = (float*)d_ws;
    bf16* HpB  = (bf16*)(ws + OFF_HPB);
    bf16* bHB  = (bf16*)(ws + OFF_BHB);
    float* cb  = ws + OFF_C;
    bf16* hB   = (bf16*)(ws + OFF_HB16);
    bf16* phB  = (bf16*)(ws + OFF_PH);
    bf16* ctxB = (bf16*)(ws + OFF_CTXB);
    bf16* WiB  = (bf16*)(ws + OFF_WIB);
    bf16* WcB  = (bf16*)(ws + OFF_WCB);
    bf16* W2B  = (bf16*)(ws + OFF_W2);
    const int* text = (const int*)d_in[1];
    float* out = (float*)d_out;

    conv_all<<<BH_BLOCKS + W_BLOCKS + Z_BLOCKS, 256, 0, stream>>>(
        (const float*)d_in[0],
        (const float*)d_in[2], (const float*)d_in[3], (const float*)d_in[4],
        (const float*)d_in[5], (const float*)d_in[6], (const float*)d_in[7],
        (const float*)d_in[8], (const float*)d_in[9], (const float*)d_in[10],
        (const float*)d_in[11], ws);

    // Hp(bf16) = batch_H @ Wi^T
    hp_gemm<<<dim3(NB * NT / 128, ND / 128), 256, 0, stream>>>(bHB, WiB, HpB);

    for (int s = 0; s < NS; ++s) {
        // [ph | probs(s-1)] = h @ [Wh;Wg]^T   M=1024, N=640, K=512
        ph_gemm<<<dim3(NB / 128, 640 / 64), 256, 0, stream>>>(
            hB, WcB, ws + OFF_BH_, ws + OFF_BG_, (unsigned short*)phB, out, s);
        attn_fused<<<NB, 256, 0, stream>>>(HpB, phB, ws + OFF_WS_, bHB,
                                           (unsigned short*)ctxB);
        // gates = [h|ctx] @ W2^T + bihh + onehot ; LSTM pointwise
        gates_lstm<<<dim3(NB / 32, NH / 64), 256, 0, stream>>>(
            hB, ctxB, W2B, ws + OFF_BIHH, ws + OFF_OH, text, s, cb,
            (unsigned short*)hB);
    }
    final_gen<<<NB, 256, 0, stream>>>(hB, WcB + (size_t)512 * 512, ws + OFF_BG_, out);
}